// Round 1
// baseline (5291.584 us; speedup 1.0000x reference)
//
#include <hip/hip_runtime.h>
#include <math.h>

#define H 128
#define BN_EPS 1e-5f

// ---------------------------------------------------------------------------
// Input projection: h = x @ W + b   (x: [N,32], W: [32,128])
// one block (128 threads) per row
// ---------------------------------------------------------------------------
__global__ __launch_bounds__(128)
void proj_kernel(const float* __restrict__ x_u, const float* __restrict__ x_r,
                 const float* __restrict__ Wu, const float* __restrict__ bu,
                 const float* __restrict__ Wr, const float* __restrict__ br,
                 float* __restrict__ h_u, float* __restrict__ h_r,
                 int Nu, int Nr) {
    __shared__ float xs[32];
    int row = blockIdx.x;
    int t = threadIdx.x;
    const float* x; const float* W; const float* b; float* out;
    if (row < Nu) {
        x = x_u + (size_t)row * 32; W = Wu; b = bu; out = h_u + (size_t)row * H;
    } else {
        int r = row - Nu;
        x = x_r + (size_t)r * 32; W = Wr; b = br; out = h_r + (size_t)r * H;
    }
    if (t < 32) xs[t] = x[t];
    __syncthreads();
    float acc = b[t];
    #pragma unroll
    for (int k = 0; k < 32; ++k) acc = fmaf(xs[k], W[k * H + t], acc);
    out[t] = acc;
}

// ---------------------------------------------------------------------------
// Scatter-add for mean aggregation: agg[dst] += h[src], cnt[dst] += 1
// 256 threads = 8 edges x 32 lanes, float4 per lane
// ---------------------------------------------------------------------------
__global__ __launch_bounds__(256)
void scatter_kernel(const float* __restrict__ hsrc, const int* __restrict__ src,
                    const int* __restrict__ dst, float* __restrict__ agg,
                    float* __restrict__ cnt, int E) {
    int e = blockIdx.x * 8 + (threadIdx.x >> 5);
    if (e >= E) return;
    int lane = threadIdx.x & 31;
    int s = src[e], d = dst[e];
    float4 v = *(const float4*)(hsrc + (size_t)s * H + lane * 4);
    float* p = agg + (size_t)d * H + lane * 4;
    atomicAdd(p + 0, v.x);
    atomicAdd(p + 1, v.y);
    atomicAdd(p + 2, v.z);
    atomicAdd(p + 3, v.w);
    if (lane == 0) atomicAdd(cnt + d, 1.0f);
}

// ---------------------------------------------------------------------------
// Fused SAGE layer (per node type), in-place on h:
//   h = relu(bn((agg/max(cnt,1)) @ Wl + bl + h @ Wr)) + h
// Tiled GEMM: BM=64 rows, BN=128 (full width), K=256 (agg||h), BK=32.
// 256 threads; each thread computes 8 rows x 4 cols.
// ---------------------------------------------------------------------------
__global__ __launch_bounds__(256)
void sage_kernel(const float* __restrict__ agg, const float* __restrict__ cnt,
                 float* __restrict__ h, int N,
                 const float* __restrict__ Wl, const float* __restrict__ bl,
                 const float* __restrict__ Wr,
                 const float* __restrict__ bng, const float* __restrict__ bnb,
                 const float* __restrict__ bnm, const float* __restrict__ bnv) {
    __shared__ float As[32][64];     // k-major A tile
    __shared__ float Bs[32][128];
    __shared__ float inv[64];
    __shared__ float sc[128], sh[128], bias[128];

    int tid = threadIdx.x;
    int row0 = blockIdx.x * 64;

    if (tid < 64) {
        int r = row0 + tid;
        float c = (r < N) ? cnt[r] : 1.0f;
        inv[tid] = 1.0f / fmaxf(c, 1.0f);
    }
    if (tid < 128) {
        float s = bng[tid] * rsqrtf(bnv[tid] + BN_EPS);
        sc[tid] = s;
        sh[tid] = bnb[tid] - bnm[tid] * s;
        bias[tid] = bl[tid];
    }

    int tx = tid & 31, ty = tid >> 5;
    int rl = tid >> 2;            // row within tile for A loads
    int kb = (tid & 3) * 8;       // 8 k's per thread
    int arow = row0 + rl;
    bool arok = arow < N;
    int kkB = tid >> 3;           // 0..31 (k row of B tile)
    int cb = (tid & 7) * 16;      // 16 cols per thread

    float acc[8][4];
    #pragma unroll
    for (int r = 0; r < 8; ++r)
        #pragma unroll
        for (int c = 0; c < 4; ++c) acc[r][c] = 0.0f;

    for (int kc = 0; kc < 8; ++kc) {
        __syncthreads();
        // A tile (scaled agg for kc<4, h for kc>=4)
        {
            float vals[8];
            if (arok) {
                const float* sp;
                float scl;
                if (kc < 4) { sp = agg + (size_t)arow * H + kc * 32 + kb; scl = inv[rl]; }
                else        { sp = h   + (size_t)arow * H + (kc - 4) * 32 + kb; scl = 1.0f; }
                float4 v0 = *(const float4*)sp;
                float4 v1 = *(const float4*)(sp + 4);
                vals[0] = v0.x * scl; vals[1] = v0.y * scl;
                vals[2] = v0.z * scl; vals[3] = v0.w * scl;
                vals[4] = v1.x * scl; vals[5] = v1.y * scl;
                vals[6] = v1.z * scl; vals[7] = v1.w * scl;
            } else {
                #pragma unroll
                for (int j = 0; j < 8; ++j) vals[j] = 0.0f;
            }
            #pragma unroll
            for (int j = 0; j < 8; ++j) As[kb + j][rl] = vals[j];
        }
        // B tile
        {
            const float* Wp = (kc < 4) ? (Wl + (size_t)(kc * 32 + kkB) * H + cb)
                                       : (Wr + (size_t)((kc - 4) * 32 + kkB) * H + cb);
            float4 w0 = *(const float4*)(Wp);
            float4 w1 = *(const float4*)(Wp + 4);
            float4 w2 = *(const float4*)(Wp + 8);
            float4 w3 = *(const float4*)(Wp + 12);
            *(float4*)&Bs[kkB][cb]      = w0;
            *(float4*)&Bs[kkB][cb + 4]  = w1;
            *(float4*)&Bs[kkB][cb + 8]  = w2;
            *(float4*)&Bs[kkB][cb + 12] = w3;
        }
        __syncthreads();
        #pragma unroll 4
        for (int k = 0; k < 32; ++k) {
            float4 b4 = *(const float4*)&Bs[k][tx * 4];
            float4 a0 = *(const float4*)&As[k][ty * 8];
            float4 a1 = *(const float4*)&As[k][ty * 8 + 4];
            float av[8] = {a0.x, a0.y, a0.z, a0.w, a1.x, a1.y, a1.z, a1.w};
            float bv[4] = {b4.x, b4.y, b4.z, b4.w};
            #pragma unroll
            for (int r = 0; r < 8; ++r)
                #pragma unroll
                for (int c = 0; c < 4; ++c)
                    acc[r][c] = fmaf(av[r], bv[c], acc[r][c]);
        }
    }

    // epilogue: bias -> BN -> ReLU -> +h, in-place store
    #pragma unroll
    for (int r = 0; r < 8; ++r) {
        int row = row0 + ty * 8 + r;
        if (row < N) {
            float* hp = h + (size_t)row * H + tx * 4;
            float4 hv = *(const float4*)hp;
            int col = tx * 4;
            float4 o;
            float z;
            z = acc[r][0] + bias[col + 0]; z = z * sc[col + 0] + sh[col + 0]; o.x = fmaxf(z, 0.0f) + hv.x;
            z = acc[r][1] + bias[col + 1]; z = z * sc[col + 1] + sh[col + 1]; o.y = fmaxf(z, 0.0f) + hv.y;
            z = acc[r][2] + bias[col + 2]; z = z * sc[col + 2] + sh[col + 2]; o.z = fmaxf(z, 0.0f) + hv.z;
            z = acc[r][3] + bias[col + 3]; z = z * sc[col + 3] + sh[col + 3]; o.w = fmaxf(z, 0.0f) + hv.w;
            *(float4*)hp = o;
        }
    }
}

// ---------------------------------------------------------------------------
// Edge predictor, fully fused per 64-edge tile:
//   x = [h_u[src] | h_r[dst] | ea]  (272)
//   h1 = bn(relu(x @ W1 + b1))            (128)
//   h2 = relu(h1 @ W2 + b2)               (64)
//   out = sigmoid(h2 @ W3 + b3)           (1)
// ---------------------------------------------------------------------------
__global__ __launch_bounds__(256)
void ep_kernel(const float* __restrict__ h_u, const float* __restrict__ h_r,
               const float* __restrict__ ea, const int* __restrict__ esrc,
               const int* __restrict__ edst,
               const float* __restrict__ W1, const float* __restrict__ b1,
               const float* __restrict__ bng, const float* __restrict__ bnb,
               const float* __restrict__ bnm, const float* __restrict__ bnv,
               const float* __restrict__ W2, const float* __restrict__ b2,
               const float* __restrict__ W3, const float* __restrict__ b3,
               float* __restrict__ out, int E) {
    union SU {
        struct { float As[32][64]; float Bs[32][128]; } s;
        float h2s[64][65];
    };
    __shared__ SU u;
    __shared__ float h1s[64][132];   // [edge][h1-dim], padded
    __shared__ int se[64], de[64];
    __shared__ float sc1[128], sh1[128], bi1[128];
    __shared__ float w3s[64];

    int tid = threadIdx.x;
    int e0 = blockIdx.x * 64;

    if (tid < 64) {
        int e = e0 + tid;
        se[tid] = (e < E) ? esrc[e] : 0;
        de[tid] = (e < E) ? edst[e] : 0;
        w3s[tid] = W3[tid];
    }
    if (tid < 128) {
        float s = bng[tid] * rsqrtf(bnv[tid] + BN_EPS);
        sc1[tid] = s;
        sh1[tid] = bnb[tid] - bnm[tid] * s;
        bi1[tid] = b1[tid];
    }

    int tx = tid & 31, ty = tid >> 5;
    int rl = tid >> 2;
    int kb = (tid & 3) * 8;
    int kkB = tid >> 3;
    int cb = (tid & 7) * 16;

    float acc[8][4];
    #pragma unroll
    for (int r = 0; r < 8; ++r)
        #pragma unroll
        for (int c = 0; c < 4; ++c) acc[r][c] = 0.0f;

    // ---- phase 1: h1 = bn(relu(x @ W1 + b1)), K = 288 (272 padded) ----
    for (int kc = 0; kc < 9; ++kc) {
        __syncthreads();
        // A tile (gathered)
        {
            int dim0 = kc * 32 + kb;
            float vals[8];
            int e = e0 + rl;
            const float* p = nullptr;
            if (dim0 < 128)      p = h_u + (size_t)se[rl] * H + dim0;
            else if (dim0 < 256) p = h_r + (size_t)de[rl] * H + (dim0 - 128);
            else if (dim0 < 272 && e < E) p = ea + (size_t)e * 16 + (dim0 - 256);
            if (p) {
                float4 v0 = *(const float4*)p;
                float4 v1 = *(const float4*)(p + 4);
                vals[0] = v0.x; vals[1] = v0.y; vals[2] = v0.z; vals[3] = v0.w;
                vals[4] = v1.x; vals[5] = v1.y; vals[6] = v1.z; vals[7] = v1.w;
            } else {
                #pragma unroll
                for (int j = 0; j < 8; ++j) vals[j] = 0.0f;
            }
            #pragma unroll
            for (int j = 0; j < 8; ++j) u.s.As[kb + j][rl] = vals[j];
        }
        // B tile
        {
            int krow = kc * 32 + kkB;
            float4 w0, w1, w2, w3;
            if (krow < 272) {
                const float* Wp = W1 + (size_t)krow * H + cb;
                w0 = *(const float4*)(Wp);
                w1 = *(const float4*)(Wp + 4);
                w2 = *(const float4*)(Wp + 8);
                w3 = *(const float4*)(Wp + 12);
            } else {
                w0 = w1 = w2 = w3 = make_float4(0.f, 0.f, 0.f, 0.f);
            }
            *(float4*)&u.s.Bs[kkB][cb]      = w0;
            *(float4*)&u.s.Bs[kkB][cb + 4]  = w1;
            *(float4*)&u.s.Bs[kkB][cb + 8]  = w2;
            *(float4*)&u.s.Bs[kkB][cb + 12] = w3;
        }
        __syncthreads();
        #pragma unroll 4
        for (int k = 0; k < 32; ++k) {
            float4 b4 = *(const float4*)&u.s.Bs[k][tx * 4];
            float4 a0 = *(const float4*)&u.s.As[k][ty * 8];
            float4 a1 = *(const float4*)&u.s.As[k][ty * 8 + 4];
            float av[8] = {a0.x, a0.y, a0.z, a0.w, a1.x, a1.y, a1.z, a1.w};
            float bv[4] = {b4.x, b4.y, b4.z, b4.w};
            #pragma unroll
            for (int r = 0; r < 8; ++r)
                #pragma unroll
                for (int c = 0; c < 4; ++c)
                    acc[r][c] = fmaf(av[r], bv[c], acc[r][c]);
        }
    }

    // phase-1 epilogue: bias -> relu -> bn -> h1s[edge][col]
    #pragma unroll
    for (int r = 0; r < 8; ++r) {
        int row = ty * 8 + r;
        int col = tx * 4;
        float4 o;
        float z;
        z = acc[r][0] + bi1[col + 0]; z = fmaxf(z, 0.0f); o.x = z * sc1[col + 0] + sh1[col + 0];
        z = acc[r][1] + bi1[col + 1]; z = fmaxf(z, 0.0f); o.y = z * sc1[col + 1] + sh1[col + 1];
        z = acc[r][2] + bi1[col + 2]; z = fmaxf(z, 0.0f); o.z = z * sc1[col + 2] + sh1[col + 2];
        z = acc[r][3] + bi1[col + 3]; z = fmaxf(z, 0.0f); o.w = z * sc1[col + 3] + sh1[col + 3];
        *(float4*)&h1s[row][col] = o;
    }

    // ---- phase 2: h2 = relu(h1 @ W2 + b2), [64,128]x[128,64] ----
    int tx2 = tid & 15, ty2 = tid >> 4;
    int kk2 = tid >> 3;            // 0..31
    int cb2 = (tid & 7) * 8;       // 0..56
    float acc2[4][4];
    #pragma unroll
    for (int r = 0; r < 4; ++r)
        #pragma unroll
        for (int c = 0; c < 4; ++c) acc2[r][c] = 0.0f;

    float* B2 = &u.s.Bs[0][0];     // reused as [32][64]
    for (int kc2 = 0; kc2 < 4; ++kc2) {
        __syncthreads();
        {
            const float* Wp = W2 + (size_t)(kc2 * 32 + kk2) * 64 + cb2;
            float4 w0 = *(const float4*)(Wp);
            float4 w1 = *(const float4*)(Wp + 4);
            *(float4*)&B2[kk2 * 64 + cb2]     = w0;
            *(float4*)&B2[kk2 * 64 + cb2 + 4] = w1;
        }
        __syncthreads();
        #pragma unroll 4
        for (int k = 0; k < 32; ++k) {
            float4 b4 = *(const float4*)&B2[k * 64 + tx2 * 4];
            float bv[4] = {b4.x, b4.y, b4.z, b4.w};
            float av[4];
            #pragma unroll
            for (int r = 0; r < 4; ++r) av[r] = h1s[ty2 * 4 + r][kc2 * 32 + k];
            #pragma unroll
            for (int r = 0; r < 4; ++r)
                #pragma unroll
                for (int c = 0; c < 4; ++c)
                    acc2[r][c] = fmaf(av[r], bv[c], acc2[r][c]);
        }
    }

    __syncthreads();   // all B2 reads done before overwriting union with h2s
    #pragma unroll
    for (int r = 0; r < 4; ++r) {
        int row = ty2 * 4 + r;
        #pragma unroll
        for (int c = 0; c < 4; ++c) {
            int col = tx2 * 4 + c;
            float z = acc2[r][c] + b2[col];
            u.h2s[row][col] = fmaxf(z, 0.0f);
        }
    }
    __syncthreads();

    // ---- phase 3: out = sigmoid(h2 @ W3 + b3) ----
    if (tid < 64) {
        int e = e0 + tid;
        if (e < E) {
            float dot = b3[0];
            #pragma unroll 8
            for (int k = 0; k < 64; ++k) dot = fmaf(u.h2s[tid][k], w3s[k], dot);
            out[e] = 1.0f / (1.0f + expf(-dot));
        }
    }
}

// ---------------------------------------------------------------------------
extern "C" void kernel_launch(void* const* d_in, const int* in_sizes, int n_in,
                              void* d_out, int out_size, void* d_ws, size_t ws_size,
                              hipStream_t stream) {
    const float* x_u     = (const float*)d_in[0];
    const float* x_r     = (const float*)d_in[1];
    const float* eattr   = (const float*)d_in[2];
    const int*   ei_ut   = (const int*)d_in[3];
    const int*   ei_ru   = (const int*)d_in[4];
    const float* proj_uW = (const float*)d_in[5];
    const float* proj_ub = (const float*)d_in[6];
    const float* proj_rW = (const float*)d_in[7];
    const float* proj_rb = (const float*)d_in[8];
    const float* sage_Wl = (const float*)d_in[9];
    const float* sage_bl = (const float*)d_in[10];
    const float* sage_Wr = (const float*)d_in[11];
    const float* bn_g    = (const float*)d_in[12];
    const float* bn_b    = (const float*)d_in[13];
    const float* bn_m    = (const float*)d_in[14];
    const float* bn_v    = (const float*)d_in[15];
    const float* ep_W1   = (const float*)d_in[16];
    const float* ep_b1   = (const float*)d_in[17];
    const float* ep_bng  = (const float*)d_in[18];
    const float* ep_bnb  = (const float*)d_in[19];
    const float* ep_bnm  = (const float*)d_in[20];
    const float* ep_bnv  = (const float*)d_in[21];
    const float* ep_W2   = (const float*)d_in[22];
    const float* ep_b2   = (const float*)d_in[23];
    const float* ep_W3   = (const float*)d_in[24];
    const float* ep_b3   = (const float*)d_in[25];

    int Nu = in_sizes[0] / 32;
    int Nr = in_sizes[1] / 32;
    int E  = in_sizes[3] / 2;

    float* ws = (float*)d_ws;
    size_t off = 0;
    float* h_u   = ws + off; off += (size_t)Nu * H;
    float* h_r   = ws + off; off += (size_t)Nr * H;
    float* agg_r = ws + off; off += (size_t)Nr * H;
    float* agg_u = ws + off; off += (size_t)Nu * H;
    float* cnt_r = ws + off; off += (size_t)Nr;
    float* cnt_u = ws + off; off += (size_t)Nu;

    const int* ut_src = ei_ut;
    const int* ut_dst = ei_ut + E;
    const int* ru_src = ei_ru;
    const int* ru_dst = ei_ru + E;

    // input projections
    proj_kernel<<<Nu + Nr, 128, 0, stream>>>(x_u, x_r, proj_uW, proj_ub,
                                             proj_rW, proj_rb, h_u, h_r, Nu, Nr);

    size_t zero_bytes = ((size_t)(Nu + Nr) * H + (size_t)Nu + (size_t)Nr) * sizeof(float);

    for (int layer = 0; layer < 2; ++layer) {
        hipMemsetAsync(agg_r, 0, zero_bytes, stream);   // agg_r, agg_u, cnt_r, cnt_u contiguous

        scatter_kernel<<<(E + 7) / 8, 256, 0, stream>>>(h_u, ut_src, ut_dst, agg_r, cnt_r, E);
        scatter_kernel<<<(E + 7) / 8, 256, 0, stream>>>(h_r, ru_src, ru_dst, agg_u, cnt_u, E);

        const float* Wl0 = sage_Wl + ((size_t)layer * 2 + 0) * H * H;
        const float* Wl1 = sage_Wl + ((size_t)layer * 2 + 1) * H * H;
        const float* bl0 = sage_bl + ((size_t)layer * 2 + 0) * H;
        const float* bl1 = sage_bl + ((size_t)layer * 2 + 1) * H;
        const float* Wr0 = sage_Wr + ((size_t)layer * 2 + 0) * H * H;
        const float* Wr1 = sage_Wr + ((size_t)layer * 2 + 1) * H * H;
        // bn node-type index: 0 = user, 1 = recipient
        const float* g_u = bn_g + ((size_t)layer * 2 + 0) * H;
        const float* b_u = bn_b + ((size_t)layer * 2 + 0) * H;
        const float* m_u = bn_m + ((size_t)layer * 2 + 0) * H;
        const float* v_u = bn_v + ((size_t)layer * 2 + 0) * H;
        const float* g_r = bn_g + ((size_t)layer * 2 + 1) * H;
        const float* b_r = bn_b + ((size_t)layer * 2 + 1) * H;
        const float* m_r = bn_m + ((size_t)layer * 2 + 1) * H;
        const float* v_r = bn_v + ((size_t)layer * 2 + 1) * H;

        // recipient update (edge type 0) — reads h_r pre-update (agg_u already captured h_r via scatter above)
        sage_kernel<<<(Nr + 63) / 64, 256, 0, stream>>>(agg_r, cnt_r, h_r, Nr,
                                                        Wl0, bl0, Wr0, g_r, b_r, m_r, v_r);
        // user update (edge type 1)
        sage_kernel<<<(Nu + 63) / 64, 256, 0, stream>>>(agg_u, cnt_u, h_u, Nu,
                                                        Wl1, bl1, Wr1, g_u, b_u, m_u, v_u);
    }

    ep_kernel<<<(E + 63) / 64, 256, 0, stream>>>(h_u, h_r, eattr, ut_src, ut_dst,
                                                 ep_W1, ep_b1,
                                                 ep_bng, ep_bnb, ep_bnm, ep_bnv,
                                                 ep_W2, ep_b2, ep_W3, ep_b3,
                                                 (float*)d_out, E);
}

// Round 2
// 1565.527 us; speedup vs baseline: 3.3801x; 3.3801x over previous
//
#include <hip/hip_runtime.h>
#include <math.h>

#define H 128
#define BN_EPS 1e-5f

// bf16 helpers (manual RTNE, no header dependency)
__device__ __forceinline__ unsigned short f2bf(float f) {
    unsigned int u = __float_as_uint(f);
    u += 0x7fffu + ((u >> 16) & 1u);
    return (unsigned short)(u >> 16);
}
__device__ __forceinline__ float bf2f(unsigned short s) {
    return __uint_as_float(((unsigned int)s) << 16);
}

// ---------------------------------------------------------------------------
// Input projection: h = x @ W + b   (x: [N,32], W: [32,128])
// ---------------------------------------------------------------------------
__global__ __launch_bounds__(128)
void proj_kernel(const float* __restrict__ x_u, const float* __restrict__ x_r,
                 const float* __restrict__ Wu, const float* __restrict__ bu,
                 const float* __restrict__ Wr, const float* __restrict__ br,
                 float* __restrict__ h_u, float* __restrict__ h_r,
                 int Nu, int Nr) {
    __shared__ float xs[32];
    int row = blockIdx.x;
    int t = threadIdx.x;
    const float* x; const float* W; const float* b; float* out;
    if (row < Nu) {
        x = x_u + (size_t)row * 32; W = Wu; b = bu; out = h_u + (size_t)row * H;
    } else {
        int r = row - Nu;
        x = x_r + (size_t)r * 32; W = Wr; b = br; out = h_r + (size_t)r * H;
    }
    if (t < 32) xs[t] = x[t];
    __syncthreads();
    float acc = b[t];
    #pragma unroll
    for (int k = 0; k < 32; ++k) acc = fmaf(xs[k], W[k * H + t], acc);
    out[t] = acc;
}

// ---------------------------------------------------------------------------
// CSR build: histogram -> scan (3 kernels) -> bucket fill
// ---------------------------------------------------------------------------
__global__ __launch_bounds__(256)
void hist_kernel(const int* __restrict__ dst, int* __restrict__ deg, int E) {
    int e = blockIdx.x * 256 + threadIdx.x;
    if (e < E) atomicAdd(&deg[dst[e]], 1);
}

__global__ __launch_bounds__(256)
void scan1_kernel(const int* __restrict__ deg, int* __restrict__ part, int N) {
    __shared__ int s[256];
    int t = threadIdx.x;
    int i = blockIdx.x * 256 + t;
    s[t] = (i < N) ? deg[i] : 0;
    __syncthreads();
    for (int o = 128; o > 0; o >>= 1) {
        if (t < o) s[t] += s[t + o];
        __syncthreads();
    }
    if (t == 0) part[blockIdx.x] = s[0];
}

__global__ __launch_bounds__(512)
void scan2_kernel(int* __restrict__ part, int nb) {   // single block, nb <= 512
    __shared__ int s[512];
    int t = threadIdx.x;
    int v = (t < nb) ? part[t] : 0;
    s[t] = v;
    __syncthreads();
    for (int o = 1; o < 512; o <<= 1) {
        int x = (t >= o) ? s[t - o] : 0;
        __syncthreads();
        s[t] += x;
        __syncthreads();
    }
    if (t < nb) part[t] = s[t] - v;   // exclusive
}

__global__ __launch_bounds__(256)
void scan3_kernel(const int* __restrict__ deg, const int* __restrict__ part,
                  int* __restrict__ off, int N) {
    __shared__ int s[256];
    int t = threadIdx.x;
    int i = blockIdx.x * 256 + t;
    int v = (i < N) ? deg[i] : 0;
    s[t] = v;
    __syncthreads();
    for (int o = 1; o < 256; o <<= 1) {
        int x = (t >= o) ? s[t - o] : 0;
        __syncthreads();
        s[t] += x;
        __syncthreads();
    }
    if (i < N) off[i] = part[blockIdx.x] + s[t] - v;
    if (i == N - 1) off[N] = part[blockIdx.x] + s[t];
}

__global__ __launch_bounds__(256)
void fill_kernel(const int* __restrict__ src, const int* __restrict__ dst,
                 const int* __restrict__ off, int* __restrict__ cur,
                 int* __restrict__ eid, int E) {
    int e = blockIdx.x * 256 + threadIdx.x;
    if (e < E) {
        int d = dst[e];
        int p = off[d] + atomicAdd(&cur[d], 1);
        eid[p] = src[e];
    }
}

// ---------------------------------------------------------------------------
// Gather-aggregate (mean): one wave per dst node, float2 per lane (128 floats)
// ---------------------------------------------------------------------------
__global__ __launch_bounds__(256)
void gather_kernel(const float* __restrict__ hsrc, const int* __restrict__ eid,
                   const int* __restrict__ off, float* __restrict__ agg, int N) {
    int node = blockIdx.x * 4 + (threadIdx.x >> 6);
    if (node >= N) return;
    int lane = threadIdx.x & 63;
    int s0 = off[node], s1 = off[node + 1];
    float ax = 0.0f, ay = 0.0f;
    for (int i = s0; i < s1; ++i) {
        int s = eid[i];
        float2 v = *(const float2*)(hsrc + (size_t)s * H + lane * 2);
        ax += v.x; ay += v.y;
    }
    float inv = (s1 > s0) ? 1.0f / (float)(s1 - s0) : 0.0f;
    float2 o; o.x = ax * inv; o.y = ay * inv;
    *(float2*)(agg + (size_t)node * H + lane * 2) = o;
}

// ---------------------------------------------------------------------------
// Fused SAGE layer, in-place on h:
//   h = relu(bn(agg @ Wl + bl + h @ Wr)) + h      (agg already mean)
// BM=64, BN=128, K=256, BK=32. 256 threads, 8x4 per thread.
// Conflict-free staging: A register-transposed (4 rows x 2k -> k-major float4),
// As stride 68 (16B aligned, banks spread); B chunks at stride-32 cols.
// ---------------------------------------------------------------------------
__global__ __launch_bounds__(256, 4)
void sage_kernel(const float* __restrict__ agg, float* __restrict__ h, int N,
                 const float* __restrict__ Wl, const float* __restrict__ bl,
                 const float* __restrict__ Wr,
                 const float* __restrict__ bng, const float* __restrict__ bnb,
                 const float* __restrict__ bnm, const float* __restrict__ bnv) {
    __shared__ float As[32][68];
    __shared__ float Bs[32][128];
    __shared__ float sc[128], sh[128], bias[128];

    int tid = threadIdx.x;
    int row0 = blockIdx.x * 64;

    if (tid < 128) {
        float s = bng[tid] * rsqrtf(bnv[tid] + BN_EPS);
        sc[tid] = s;
        sh[tid] = bnb[tid] - bnm[tid] * s;
        bias[tid] = bl[tid];
    }

    int tx = tid & 31, ty = tid >> 5;
    int kg = tid & 15;            // k-pair index (k = 2*kg)
    int rg = tid >> 4;            // row-group 0..15 (rows rg*4..+3)
    int krB = tid >> 3;           // B k-row 0..31
    int cbB = (tid & 7) * 4;      // B col base

    float acc[8][4];
    #pragma unroll
    for (int r = 0; r < 8; ++r)
        #pragma unroll
        for (int c = 0; c < 4; ++c) acc[r][c] = 0.0f;

    for (int kc = 0; kc < 8; ++kc) {
        __syncthreads();
        // A tile: register transpose, k-major float4 writes
        {
            const float* src = (kc < 4) ? agg : h;
            int koff = (kc & 3) * 32 + kg * 2;
            float2 v[4];
            #pragma unroll
            for (int i = 0; i < 4; ++i) {
                int row = row0 + rg * 4 + i;
                if (row < N) v[i] = *(const float2*)(src + (size_t)row * H + koff);
                else         v[i] = make_float2(0.f, 0.f);
            }
            *(float4*)&As[kg * 2 + 0][rg * 4] = make_float4(v[0].x, v[1].x, v[2].x, v[3].x);
            *(float4*)&As[kg * 2 + 1][rg * 4] = make_float4(v[0].y, v[1].y, v[2].y, v[3].y);
        }
        // B tile: 4 chunks at stride-32 columns
        {
            const float* Wbase = (kc < 4) ? Wl : Wr;
            const float* Wp = Wbase + (size_t)((kc & 3) * 32 + krB) * H + cbB;
            #pragma unroll
            for (int c = 0; c < 4; ++c)
                *(float4*)&Bs[krB][cbB + 32 * c] = *(const float4*)(Wp + 32 * c);
        }
        __syncthreads();
        #pragma unroll 4
        for (int k = 0; k < 32; ++k) {
            float4 b4 = *(const float4*)&Bs[k][tx * 4];
            float4 a0 = *(const float4*)&As[k][ty * 8];
            float4 a1 = *(const float4*)&As[k][ty * 8 + 4];
            float av[8] = {a0.x, a0.y, a0.z, a0.w, a1.x, a1.y, a1.z, a1.w};
            float bv[4] = {b4.x, b4.y, b4.z, b4.w};
            #pragma unroll
            for (int r = 0; r < 8; ++r)
                #pragma unroll
                for (int c = 0; c < 4; ++c)
                    acc[r][c] = fmaf(av[r], bv[c], acc[r][c]);
        }
    }

    // epilogue: bias -> BN -> ReLU -> +h
    #pragma unroll
    for (int r = 0; r < 8; ++r) {
        int row = row0 + ty * 8 + r;
        if (row < N) {
            float* hp = h + (size_t)row * H + tx * 4;
            float4 hv = *(const float4*)hp;
            int col = tx * 4;
            float4 o; float z;
            z = acc[r][0] + bias[col + 0]; z = z * sc[col + 0] + sh[col + 0]; o.x = fmaxf(z, 0.0f) + hv.x;
            z = acc[r][1] + bias[col + 1]; z = z * sc[col + 1] + sh[col + 1]; o.y = fmaxf(z, 0.0f) + hv.y;
            z = acc[r][2] + bias[col + 2]; z = z * sc[col + 2] + sh[col + 2]; o.z = fmaxf(z, 0.0f) + hv.z;
            z = acc[r][3] + bias[col + 3]; z = z * sc[col + 3] + sh[col + 3]; o.w = fmaxf(z, 0.0f) + hv.w;
            *(float4*)hp = o;
        }
    }
}

// ---------------------------------------------------------------------------
// Edge predictor, fused per 64-edge tile, overlapped LDS (27.4 KB total):
//   phase1: h1 = bn(relu([h_u[s]|h_r[d]|ea] @ W1 + b1))  (K=272, bf16 h1)
//   phase2: h2 = relu(h1 @ W2 + b2)
//   phase3: out = sigmoid(h2 @ W3 + b3)
// ---------------------------------------------------------------------------
__global__ __launch_bounds__(256, 4)
void ep_kernel(const float* __restrict__ h_u, const float* __restrict__ h_r,
               const float* __restrict__ ea, const int* __restrict__ esrc,
               const int* __restrict__ edst,
               const float* __restrict__ W1, const float* __restrict__ b1,
               const float* __restrict__ bng, const float* __restrict__ bnb,
               const float* __restrict__ bnm, const float* __restrict__ bnv,
               const float* __restrict__ W2, const float* __restrict__ b2,
               const float* __restrict__ W3, const float* __restrict__ b3,
               float* __restrict__ out, int E) {
    __shared__ __align__(16) char pool[25088];
    float (*As)[68]  = (float(*)[68])pool;                       // 8704 B
    float (*Bs)[128] = (float(*)[128])(pool + 8704);             // 16384 B (phase1)
    unsigned short (*h1s)[132] = (unsigned short(*)[132])pool;   // 16896 B (phase2, over As/Bs-head)
    float (*B2)[64]  = (float(*)[64])(pool + 16896);             // 8192 B (phase2, over Bs-tail)
    float (*h2s)[65] = (float(*)[65])pool;                       // 16640 B (phase3, over h1s)
    __shared__ int se[64], de[64];
    __shared__ float sc1[128], sh1[128], bi1[128], w3s[64];

    int tid = threadIdx.x;
    int e0 = blockIdx.x * 64;

    if (tid < 64) {
        int e = e0 + tid;
        se[tid] = (e < E) ? esrc[e] : 0;
        de[tid] = (e < E) ? edst[e] : 0;
        w3s[tid] = W3[tid];
    }
    if (tid < 128) {
        float s = bng[tid] * rsqrtf(bnv[tid] + BN_EPS);
        sc1[tid] = s;
        sh1[tid] = bnb[tid] - bnm[tid] * s;
        bi1[tid] = b1[tid];
    }
    __syncthreads();

    int tx = tid & 31, ty = tid >> 5;
    int kg = tid & 15, rg = tid >> 4;
    int krB = tid >> 3;
    int cbB = (tid & 7) * 4;

    // cache row indices for this thread's 4 A-rows
    int su[4], du[4]; bool ev[4]; const float* pe[4];
    #pragma unroll
    for (int i = 0; i < 4; ++i) {
        int row = rg * 4 + i;
        su[i] = se[row] * H;
        du[i] = de[row] * H;
        int e = e0 + row;
        ev[i] = (e < E);
        pe[i] = ea + (size_t)e * 16;
    }

    float acc[8][4];
    #pragma unroll
    for (int r = 0; r < 8; ++r)
        #pragma unroll
        for (int c = 0; c < 4; ++c) acc[r][c] = 0.0f;

    // ---- phase 1: K = 272 (9 chunks of 32, last padded) ----
    for (int kc = 0; kc < 9; ++kc) {
        __syncthreads();
        // A tile
        {
            float2 v[4];
            if (kc < 8) {
                int koff = (kc & 3) * 32 + kg * 2;
                #pragma unroll
                for (int i = 0; i < 4; ++i) {
                    const float* p = (kc < 4) ? (h_u + su[i]) : (h_r + du[i]);
                    v[i] = *(const float2*)(p + koff);
                }
            } else {
                #pragma unroll
                for (int i = 0; i < 4; ++i)
                    v[i] = (kg < 8 && ev[i]) ? *(const float2*)(pe[i] + kg * 2)
                                             : make_float2(0.f, 0.f);
            }
            *(float4*)&As[kg * 2 + 0][rg * 4] = make_float4(v[0].x, v[1].x, v[2].x, v[3].x);
            *(float4*)&As[kg * 2 + 1][rg * 4] = make_float4(v[0].y, v[1].y, v[2].y, v[3].y);
        }
        // B tile
        {
            int krow = kc * 32 + krB;
            if (krow < 272) {
                const float* Wp = W1 + (size_t)krow * H + cbB;
                #pragma unroll
                for (int c = 0; c < 4; ++c)
                    *(float4*)&Bs[krB][cbB + 32 * c] = *(const float4*)(Wp + 32 * c);
            } else {
                float4 z = make_float4(0.f, 0.f, 0.f, 0.f);
                #pragma unroll
                for (int c = 0; c < 4; ++c)
                    *(float4*)&Bs[krB][cbB + 32 * c] = z;
            }
        }
        __syncthreads();
        #pragma unroll 4
        for (int k = 0; k < 32; ++k) {
            float4 b4 = *(const float4*)&Bs[k][tx * 4];
            float4 a0 = *(const float4*)&As[k][ty * 8];
            float4 a1 = *(const float4*)&As[k][ty * 8 + 4];
            float av[8] = {a0.x, a0.y, a0.z, a0.w, a1.x, a1.y, a1.z, a1.w};
            float bv[4] = {b4.x, b4.y, b4.z, b4.w};
            #pragma unroll
            for (int r = 0; r < 8; ++r)
                #pragma unroll
                for (int c = 0; c < 4; ++c)
                    acc[r][c] = fmaf(av[r], bv[c], acc[r][c]);
        }
    }

    __syncthreads();   // As/Bs dead; safe to overlay h1s
    // phase-1 epilogue: bias -> relu -> bn -> bf16 h1s
    #pragma unroll
    for (int r = 0; r < 8; ++r) {
        int row = ty * 8 + r;
        int col = tx * 4;
        ushort4 o; float z;
        z = acc[r][0] + bi1[col + 0]; z = fmaxf(z, 0.0f); o.x = f2bf(z * sc1[col + 0] + sh1[col + 0]);
        z = acc[r][1] + bi1[col + 1]; z = fmaxf(z, 0.0f); o.y = f2bf(z * sc1[col + 1] + sh1[col + 1]);
        z = acc[r][2] + bi1[col + 2]; z = fmaxf(z, 0.0f); o.z = f2bf(z * sc1[col + 2] + sh1[col + 2]);
        z = acc[r][3] + bi1[col + 3]; z = fmaxf(z, 0.0f); o.w = f2bf(z * sc1[col + 3] + sh1[col + 3]);
        *(ushort4*)&h1s[row][col] = o;
    }

    // ---- phase 2: h2 = relu(h1 @ W2 + b2), [64,128]x[128,64] ----
    int tx2 = tid & 15, ty2 = tid >> 4;
    int kr2 = tid >> 3;
    int cb2 = (tid & 7) * 4;
    float acc2[4][4];
    #pragma unroll
    for (int r = 0; r < 4; ++r)
        #pragma unroll
        for (int c = 0; c < 4; ++c) acc2[r][c] = 0.0f;

    for (int kc2 = 0; kc2 < 4; ++kc2) {
        __syncthreads();
        {
            const float* Wp = W2 + (size_t)(kc2 * 32 + kr2) * 64 + cb2;
            *(float4*)&B2[kr2][cb2]      = *(const float4*)(Wp);
            *(float4*)&B2[kr2][cb2 + 32] = *(const float4*)(Wp + 32);
        }
        __syncthreads();
        #pragma unroll 4
        for (int k = 0; k < 32; ++k) {
            float4 b4 = *(const float4*)&B2[k][tx2 * 4];
            float bv[4] = {b4.x, b4.y, b4.z, b4.w};
            float av[4];
            #pragma unroll
            for (int r = 0; r < 4; ++r) av[r] = bf2f(h1s[ty2 * 4 + r][kc2 * 32 + k]);
            #pragma unroll
            for (int r = 0; r < 4; ++r)
                #pragma unroll
                for (int c = 0; c < 4; ++c)
                    acc2[r][c] = fmaf(av[r], bv[c], acc2[r][c]);
        }
    }

    __syncthreads();   // h1s/B2 reads done; overlay h2s
    #pragma unroll
    for (int r = 0; r < 4; ++r) {
        int row = ty2 * 4 + r;
        #pragma unroll
        for (int c = 0; c < 4; ++c) {
            int col = tx2 * 4 + c;
            h2s[row][col] = fmaxf(acc2[r][c] + b2[col], 0.0f);
        }
    }
    __syncthreads();

    // ---- phase 3 ----
    if (tid < 64) {
        int e = e0 + tid;
        if (e < E) {
            float dot = b3[0];
            #pragma unroll 8
            for (int k = 0; k < 64; ++k) dot = fmaf(h2s[tid][k], w3s[k], dot);
            out[e] = 1.0f / (1.0f + expf(-dot));
        }
    }
}

// ---------------------------------------------------------------------------
extern "C" void kernel_launch(void* const* d_in, const int* in_sizes, int n_in,
                              void* d_out, int out_size, void* d_ws, size_t ws_size,
                              hipStream_t stream) {
    const float* x_u     = (const float*)d_in[0];
    const float* x_r     = (const float*)d_in[1];
    const float* eattr   = (const float*)d_in[2];
    const int*   ei_ut   = (const int*)d_in[3];
    const int*   ei_ru   = (const int*)d_in[4];
    const float* proj_uW = (const float*)d_in[5];
    const float* proj_ub = (const float*)d_in[6];
    const float* proj_rW = (const float*)d_in[7];
    const float* proj_rb = (const float*)d_in[8];
    const float* sage_Wl = (const float*)d_in[9];
    const float* sage_bl = (const float*)d_in[10];
    const float* sage_Wr = (const float*)d_in[11];
    const float* bn_g    = (const float*)d_in[12];
    const float* bn_b    = (const float*)d_in[13];
    const float* bn_m    = (const float*)d_in[14];
    const float* bn_v    = (const float*)d_in[15];
    const float* ep_W1   = (const float*)d_in[16];
    const float* ep_b1   = (const float*)d_in[17];
    const float* ep_bng  = (const float*)d_in[18];
    const float* ep_bnb  = (const float*)d_in[19];
    const float* ep_bnm  = (const float*)d_in[20];
    const float* ep_bnv  = (const float*)d_in[21];
    const float* ep_W2   = (const float*)d_in[22];
    const float* ep_b2   = (const float*)d_in[23];
    const float* ep_W3   = (const float*)d_in[24];
    const float* ep_b3   = (const float*)d_in[25];

    int Nu = in_sizes[0] / 32;
    int Nr = in_sizes[1] / 32;
    int E  = in_sizes[3] / 2;

    float* ws = (float*)d_ws;
    float* h_u   = ws;
    float* h_r   = h_u + (size_t)Nu * H;
    float* agg_r = h_r + (size_t)Nr * H;
    float* agg_u = agg_r + (size_t)Nr * H;
    int* ip     = (int*)(agg_u + (size_t)Nu * H);
    int* off_r  = ip;  ip += Nr + 1;
    int* off_u  = ip;  ip += Nu + 1;
    int* cur_r  = ip;  ip += Nr;      // cur_r/cur_u contiguous (one memset)
    int* cur_u  = ip;  ip += Nu;
    int* eid_r  = ip;  ip += E;
    int* eid_u  = ip;  ip += E;
    int* part   = ip;  ip += 512;

    const int* ut_src = ei_ut;
    const int* ut_dst = ei_ut + E;
    const int* ru_src = ei_ru;
    const int* ru_dst = ei_ru + E;

    int EB  = (E + 255) / 256;
    int NBr = (Nr + 255) / 256;
    int NBu = (Nu + 255) / 256;

    // ---- CSR build (graph is identical for both layers) ----
    hipMemsetAsync(cur_r, 0, (size_t)(Nr + Nu) * sizeof(int), stream);
    hist_kernel<<<EB, 256, 0, stream>>>(ut_dst, cur_r, E);
    hist_kernel<<<EB, 256, 0, stream>>>(ru_dst, cur_u, E);
    scan1_kernel<<<NBr, 256, 0, stream>>>(cur_r, part, Nr);
    scan2_kernel<<<1, 512, 0, stream>>>(part, NBr);
    scan3_kernel<<<NBr, 256, 0, stream>>>(cur_r, part, off_r, Nr);
    scan1_kernel<<<NBu, 256, 0, stream>>>(cur_u, part, Nu);
    scan2_kernel<<<1, 512, 0, stream>>>(part, NBu);
    scan3_kernel<<<NBu, 256, 0, stream>>>(cur_u, part, off_u, Nu);
    hipMemsetAsync(cur_r, 0, (size_t)(Nr + Nu) * sizeof(int), stream);
    fill_kernel<<<EB, 256, 0, stream>>>(ut_src, ut_dst, off_r, cur_r, eid_r, E);
    fill_kernel<<<EB, 256, 0, stream>>>(ru_src, ru_dst, off_u, cur_u, eid_u, E);

    // ---- input projections ----
    proj_kernel<<<Nu + Nr, 128, 0, stream>>>(x_u, x_r, proj_uW, proj_ub,
                                             proj_rW, proj_rb, h_u, h_r, Nu, Nr);

    for (int layer = 0; layer < 2; ++layer) {
        gather_kernel<<<(Nr + 3) / 4, 256, 0, stream>>>(h_u, eid_r, off_r, agg_r, Nr);
        gather_kernel<<<(Nu + 3) / 4, 256, 0, stream>>>(h_r, eid_u, off_u, agg_u, Nu);

        const float* Wl0 = sage_Wl + ((size_t)layer * 2 + 0) * H * H;
        const float* Wl1 = sage_Wl + ((size_t)layer * 2 + 1) * H * H;
        const float* bl0 = sage_bl + ((size_t)layer * 2 + 0) * H;
        const float* bl1 = sage_bl + ((size_t)layer * 2 + 1) * H;
        const float* Wr0 = sage_Wr + ((size_t)layer * 2 + 0) * H * H;
        const float* Wr1 = sage_Wr + ((size_t)layer * 2 + 1) * H * H;
        const float* g_u = bn_g + ((size_t)layer * 2 + 0) * H;
        const float* b_u = bn_b + ((size_t)layer * 2 + 0) * H;
        const float* m_u = bn_m + ((size_t)layer * 2 + 0) * H;
        const float* v_u = bn_v + ((size_t)layer * 2 + 0) * H;
        const float* g_r = bn_g + ((size_t)layer * 2 + 1) * H;
        const float* b_r = bn_b + ((size_t)layer * 2 + 1) * H;
        const float* m_r = bn_m + ((size_t)layer * 2 + 1) * H;
        const float* v_r = bn_v + ((size_t)layer * 2 + 1) * H;

        sage_kernel<<<(Nr + 63) / 64, 256, 0, stream>>>(agg_r, h_r, Nr,
                                                        Wl0, bl0, Wr0, g_r, b_r, m_r, v_r);
        sage_kernel<<<(Nu + 63) / 64, 256, 0, stream>>>(agg_u, h_u, Nu,
                                                        Wl1, bl1, Wr1, g_u, b_u, m_u, v_u);
    }

    ep_kernel<<<(E + 63) / 64, 256, 0, stream>>>(h_u, h_r, eattr, ut_src, ut_dst,
                                                 ep_W1, ep_b1,
                                                 ep_bng, ep_bnb, ep_bnm, ep_bnv,
                                                 ep_W2, ep_b2, ep_W3, ep_b3,
                                                 (float*)d_out, E);
}

// Round 3
// 828.217 us; speedup vs baseline: 6.3891x; 1.8902x over previous
//
#include <hip/hip_runtime.h>
#include <math.h>

#define H 128
#define BN_EPS 1e-5f

typedef __attribute__((ext_vector_type(8))) short bf16x8;
typedef __attribute__((ext_vector_type(4))) float f32x4;

__device__ __forceinline__ unsigned short f2bf(float f) {
    unsigned int u = __float_as_uint(f);
    u += 0x7fffu + ((u >> 16) & 1u);
    return (unsigned short)(u >> 16);
}
__device__ __forceinline__ float bf2f(unsigned short s) {
    return __uint_as_float(((unsigned int)s) << 16);
}
__device__ __forceinline__ f32x4 mfma16(bf16x8 a, bf16x8 b, f32x4 c) {
    return __builtin_amdgcn_mfma_f32_16x16x32_bf16(a, b, c, 0, 0, 0);
}

// ---------------------------------------------------------------------------
// Weight fragment pre-transpose: dst[kc][nt][lane][j] = src[kc*32+(l>>4)*8+j][nt*16+(l&15)]
// (MFMA B-operand layout, bf16, zero-padded for k >= K)
// ---------------------------------------------------------------------------
__device__ __forceinline__ void wfrag_one(const float* __restrict__ src,
                                          unsigned short* __restrict__ dst,
                                          int K, int N, int idx) {
    int l = idx & 63;
    int rest = idx >> 6;
    int ntn = N >> 4;
    int nt = rest % ntn;
    int kc = rest / ntn;
    int n = nt * 16 + (l & 15);
    int k0 = kc * 32 + (l >> 4) * 8;
    bf16x8 v;
    #pragma unroll
    for (int j = 0; j < 8; ++j) {
        int k = k0 + j;
        v[j] = (short)((k < K) ? f2bf(src[(size_t)k * N + n]) : 0);
    }
    *(bf16x8*)(dst + (size_t)idx * 8) = v;
}

__global__ __launch_bounds__(256)
void wfrag_misc(const float* __restrict__ W1, const float* __restrict__ W2,
                const float* __restrict__ pu, const float* __restrict__ pr,
                unsigned short* __restrict__ W1f, unsigned short* __restrict__ W2f,
                unsigned short* __restrict__ puf, unsigned short* __restrict__ prf) {
    int idx = blockIdx.x * 256 + threadIdx.x;
    if (idx < 4608)      wfrag_one(W1, W1f, 272, 128, idx);            // K=272 pad 288, N=128
    else if (idx < 5632) wfrag_one(W2, W2f, 128, 64, idx - 4608);      // K=128, N=64
    else if (idx < 6144) wfrag_one(pu, puf, 32, 128, idx - 5632);      // K=32,  N=128
    else if (idx < 6656) wfrag_one(pr, prf, 32, 128, idx - 6144);
}

__global__ __launch_bounds__(256)
void wfrag_sage(const float* __restrict__ Wl, const float* __restrict__ Wr,
                unsigned short* __restrict__ Wf) {
    int idx = blockIdx.x * 256 + threadIdx.x;   // < 16384
    int seg = idx >> 11;                        // 0..7
    int sub = idx & 2047;
    int lt = seg >> 1;                          // layer*2+type
    int half = seg & 1;                         // 0=Wl (k 0..127), 1=Wr (k 128..255)
    const float* src = (half ? Wr : Wl) + (size_t)lt * H * H;
    unsigned short* dst = Wf + (size_t)lt * 32768 + half * 16384;
    wfrag_one(src, dst, 128, 128, sub);
}

// ---------------------------------------------------------------------------
// Input projection via MFMA: h = x @ W + b, dual-store fp32 + bf16
// block = 64 rows, 4 waves x (16 rows, 8 n-tiles), K=32 (single chunk)
// ---------------------------------------------------------------------------
__global__ __launch_bounds__(256)
void proj_kernel(const float* __restrict__ xu, const float* __restrict__ xr,
                 const unsigned short* __restrict__ puf, const float* __restrict__ bu,
                 const unsigned short* __restrict__ prf, const float* __restrict__ br,
                 float* __restrict__ h_u, float* __restrict__ h_r,
                 unsigned short* __restrict__ hub, unsigned short* __restrict__ hrb,
                 int Nu, int Nr, int nbu) {
    int bx = blockIdx.x;
    const float* x; const unsigned short* Wf; const float* bias;
    float* h; unsigned short* hb; int N; int row0;
    if (bx < nbu) { x = xu; Wf = puf; bias = bu; h = h_u; hb = hub; N = Nu; row0 = bx * 64; }
    else          { x = xr; Wf = prf; bias = br; h = h_r; hb = hrb; N = Nr; row0 = (bx - nbu) * 64; }

    int tid = threadIdx.x, l = tid & 63, w = tid >> 6, l15 = l & 15, quad = l >> 4;
    int arow = row0 + w * 16 + l15;

    bf16x8 a = {0, 0, 0, 0, 0, 0, 0, 0};
    if (arow < N) {
        const float* xp = x + (size_t)arow * 32 + quad * 8;
        float4 v0 = *(const float4*)xp;
        float4 v1 = *(const float4*)(xp + 4);
        a[0] = (short)f2bf(v0.x); a[1] = (short)f2bf(v0.y);
        a[2] = (short)f2bf(v0.z); a[3] = (short)f2bf(v0.w);
        a[4] = (short)f2bf(v1.x); a[5] = (short)f2bf(v1.y);
        a[6] = (short)f2bf(v1.z); a[7] = (short)f2bf(v1.w);
    }
    f32x4 acc[8];
    #pragma unroll
    for (int nt = 0; nt < 8; ++nt) {
        bf16x8 b = *(const bf16x8*)(Wf + (size_t)(nt * 64 + l) * 8);
        acc[nt] = mfma16(a, b, (f32x4){0.f, 0.f, 0.f, 0.f});
    }
    #pragma unroll
    for (int reg = 0; reg < 4; ++reg) {
        int row = row0 + w * 16 + quad * 4 + reg;
        if (row < N) {
            #pragma unroll
            for (int nt = 0; nt < 8; ++nt) {
                int col = nt * 16 + l15;
                float v = acc[nt][reg] + bias[col];
                h[(size_t)row * H + col] = v;
                hb[(size_t)row * H + col] = f2bf(v);
            }
        }
    }
}

// ---------------------------------------------------------------------------
// CSR build: histogram -> scan (3 kernels) -> bucket fill
// ---------------------------------------------------------------------------
__global__ __launch_bounds__(256)
void hist_kernel(const int* __restrict__ dst, int* __restrict__ deg, int E) {
    int e = blockIdx.x * 256 + threadIdx.x;
    if (e < E) atomicAdd(&deg[dst[e]], 1);
}

__global__ __launch_bounds__(256)
void scan1_kernel(const int* __restrict__ deg, int* __restrict__ part, int N) {
    __shared__ int s[256];
    int t = threadIdx.x;
    int i = blockIdx.x * 256 + t;
    s[t] = (i < N) ? deg[i] : 0;
    __syncthreads();
    for (int o = 128; o > 0; o >>= 1) {
        if (t < o) s[t] += s[t + o];
        __syncthreads();
    }
    if (t == 0) part[blockIdx.x] = s[0];
}

__global__ __launch_bounds__(512)
void scan2_kernel(int* __restrict__ part, int nb) {
    __shared__ int s[512];
    int t = threadIdx.x;
    int v = (t < nb) ? part[t] : 0;
    s[t] = v;
    __syncthreads();
    for (int o = 1; o < 512; o <<= 1) {
        int x = (t >= o) ? s[t - o] : 0;
        __syncthreads();
        s[t] += x;
        __syncthreads();
    }
    if (t < nb) part[t] = s[t] - v;
}

__global__ __launch_bounds__(256)
void scan3_kernel(const int* __restrict__ deg, const int* __restrict__ part,
                  int* __restrict__ off, int N) {
    __shared__ int s[256];
    int t = threadIdx.x;
    int i = blockIdx.x * 256 + t;
    int v = (i < N) ? deg[i] : 0;
    s[t] = v;
    __syncthreads();
    for (int o = 1; o < 256; o <<= 1) {
        int x = (t >= o) ? s[t - o] : 0;
        __syncthreads();
        s[t] += x;
        __syncthreads();
    }
    if (i < N) off[i] = part[blockIdx.x] + s[t] - v;
    if (i == N - 1) off[N] = part[blockIdx.x] + s[t];
}

__global__ __launch_bounds__(256)
void fill_kernel(const int* __restrict__ src, const int* __restrict__ dst,
                 const int* __restrict__ off, int* __restrict__ cur,
                 int* __restrict__ eid, int E) {
    int e = blockIdx.x * 256 + threadIdx.x;
    if (e < E) {
        int d = dst[e];
        int p = off[d] + atomicAdd(&cur[d], 1);
        eid[p] = src[e];
    }
}

// ---------------------------------------------------------------------------
// Gather-mean (bf16 in/out): one wave per dst node, ushort2 per lane
// ---------------------------------------------------------------------------
__global__ __launch_bounds__(256)
void gather_kernel(const unsigned short* __restrict__ hb, const int* __restrict__ eid,
                   const int* __restrict__ off, unsigned short* __restrict__ aggb, int N) {
    int node = blockIdx.x * 4 + (threadIdx.x >> 6);
    if (node >= N) return;
    int lane = threadIdx.x & 63;
    int s0 = off[node], s1 = off[node + 1];
    float a0 = 0.f, a1 = 0.f;
    for (int i = s0; i < s1; ++i) {
        int s = eid[i];
        unsigned int v = *(const unsigned int*)(hb + (size_t)s * H + lane * 2);
        a0 += bf2f((unsigned short)(v & 0xffffu));
        a1 += bf2f((unsigned short)(v >> 16));
    }
    float inv = (s1 > s0) ? 1.0f / (float)(s1 - s0) : 0.0f;
    unsigned int o = (unsigned int)f2bf(a0 * inv) | ((unsigned int)f2bf(a1 * inv) << 16);
    *(unsigned int*)(aggb + (size_t)node * H + lane * 2) = o;
}

// ---------------------------------------------------------------------------
// Fused SAGE layer via MFMA, in-place on h (fp32) + hb (bf16):
//   h = relu(bn(agg @ Wl + bl + h @ Wr)) + h
// block = 64 rows, K=256 (agg||h) in 8 chunks; A direct per-lane gathers,
// B direct from pre-transposed fragment layout (no LDS GEMM staging).
// ---------------------------------------------------------------------------
__global__ __launch_bounds__(256)
void sage_kernel(const unsigned short* __restrict__ aggb, float* __restrict__ h,
                 unsigned short* __restrict__ hb, int N,
                 const unsigned short* __restrict__ Wf, const float* __restrict__ bl,
                 const float* __restrict__ bng, const float* __restrict__ bnb,
                 const float* __restrict__ bnm, const float* __restrict__ bnv) {
    __shared__ float sc[128], sh[128], bias[128];
    int tid = threadIdx.x;
    if (tid < 128) {
        float s = bng[tid] * rsqrtf(bnv[tid] + BN_EPS);
        sc[tid] = s;
        sh[tid] = bnb[tid] - bnm[tid] * s;
        bias[tid] = bl[tid];
    }
    __syncthreads();

    int l = tid & 63, w = tid >> 6, l15 = l & 15, quad = l >> 4;
    int row0 = blockIdx.x * 64;
    int arow = row0 + w * 16 + l15;
    size_t r = (arow < N) ? (size_t)arow : 0;

    f32x4 acc[8];
    #pragma unroll
    for (int nt = 0; nt < 8; ++nt) acc[nt] = (f32x4){0.f, 0.f, 0.f, 0.f};

    #pragma unroll
    for (int kc = 0; kc < 8; ++kc) {
        const unsigned short* ap = ((kc < 4) ? aggb : hb) + r * H + (kc & 3) * 32 + quad * 8;
        bf16x8 a = *(const bf16x8*)ap;
        #pragma unroll
        for (int nt = 0; nt < 8; ++nt) {
            bf16x8 b = *(const bf16x8*)(Wf + (size_t)((kc * 8 + nt) * 64 + l) * 8);
            acc[nt] = mfma16(a, b, acc[nt]);
        }
    }

    #pragma unroll
    for (int reg = 0; reg < 4; ++reg) {
        int row = row0 + w * 16 + quad * 4 + reg;
        if (row < N) {
            #pragma unroll
            for (int nt = 0; nt < 8; ++nt) {
                int col = nt * 16 + l15;
                float g = acc[nt][reg] + bias[col];
                g = g * sc[col] + sh[col];
                float hv = h[(size_t)row * H + col];
                float o = fmaxf(g, 0.0f) + hv;
                h[(size_t)row * H + col] = o;
                hb[(size_t)row * H + col] = f2bf(o);
            }
        }
    }
}

// ---------------------------------------------------------------------------
// Edge predictor via MFMA, fused per 64-edge tile:
//   phase1: h1 = bn(relu([h_u[s]|h_r[d]|ea] @ W1 + b1))   K=272 (9 chunks)
//   phase2: h2 = relu(h1 @ W2 + b2)                        K=128
//   phase3: out = sigmoid(h2 @ W3 + b3)  (in-register shuffle reduction)
// ---------------------------------------------------------------------------
__global__ __launch_bounds__(256)
void ep_kernel(const unsigned short* __restrict__ hub, const unsigned short* __restrict__ hrb,
               const float* __restrict__ ea, const int* __restrict__ esrc,
               const int* __restrict__ edst,
               const unsigned short* __restrict__ W1f, const float* __restrict__ b1,
               const float* __restrict__ bng, const float* __restrict__ bnb,
               const float* __restrict__ bnm, const float* __restrict__ bnv,
               const unsigned short* __restrict__ W2f, const float* __restrict__ b2,
               const float* __restrict__ W3, const float* __restrict__ b3,
               float* __restrict__ out, int E) {
    __shared__ unsigned short h1s[64][136];   // stride 136 -> 2-way (free) frag reads
    __shared__ int se[64], de[64];
    __shared__ float sc1[128], sh1[128], bi1[128];

    int tid = threadIdx.x;
    int e0 = blockIdx.x * 64;
    if (tid < 64) {
        int e = e0 + tid;
        se[tid] = (e < E) ? esrc[e] : 0;
        de[tid] = (e < E) ? edst[e] : 0;
    }
    if (tid < 128) {
        float s = bng[tid] * rsqrtf(bnv[tid] + BN_EPS);
        sc1[tid] = s;
        sh1[tid] = bnb[tid] - bnm[tid] * s;
        bi1[tid] = b1[tid];
    }
    __syncthreads();

    int l = tid & 63, w = tid >> 6, l15 = l & 15, quad = l >> 4;
    int arow = w * 16 + l15;
    size_t soff = (size_t)se[arow] * H;
    size_t doff = (size_t)de[arow] * H;
    int e = e0 + arow;
    bool ev = (e < E);

    f32x4 acc[8];
    #pragma unroll
    for (int nt = 0; nt < 8; ++nt) acc[nt] = (f32x4){0.f, 0.f, 0.f, 0.f};

    #pragma unroll
    for (int kc = 0; kc < 9; ++kc) {
        bf16x8 a;
        if (kc < 4) {
            a = *(const bf16x8*)(hub + soff + kc * 32 + quad * 8);
        } else if (kc < 8) {
            a = *(const bf16x8*)(hrb + doff + (kc - 4) * 32 + quad * 8);
        } else {
            a = (bf16x8){0, 0, 0, 0, 0, 0, 0, 0};
            if (quad < 2 && ev) {
                const float* p = ea + (size_t)e * 16 + quad * 8;
                float4 v0 = *(const float4*)p;
                float4 v1 = *(const float4*)(p + 4);
                a[0] = (short)f2bf(v0.x); a[1] = (short)f2bf(v0.y);
                a[2] = (short)f2bf(v0.z); a[3] = (short)f2bf(v0.w);
                a[4] = (short)f2bf(v1.x); a[5] = (short)f2bf(v1.y);
                a[6] = (short)f2bf(v1.z); a[7] = (short)f2bf(v1.w);
            }
        }
        #pragma unroll
        for (int nt = 0; nt < 8; ++nt) {
            bf16x8 b = *(const bf16x8*)(W1f + (size_t)((kc * 8 + nt) * 64 + l) * 8);
            acc[nt] = mfma16(a, b, acc[nt]);
        }
    }

    // phase-1 epilogue: bias -> relu -> bn -> bf16 h1s
    #pragma unroll
    for (int nt = 0; nt < 8; ++nt) {
        #pragma unroll
        for (int reg = 0; reg < 4; ++reg) {
            int row = w * 16 + quad * 4 + reg;
            int col = nt * 16 + l15;
            float z = acc[nt][reg] + bi1[col];
            z = fmaxf(z, 0.0f);
            z = z * sc1[col] + sh1[col];
            h1s[row][col] = f2bf(z);
        }
    }
    __syncthreads();

    // phase 2: h2 = relu(h1 @ W2 + b2), K=128, N=64
    f32x4 acc2[4];
    #pragma unroll
    for (int nt = 0; nt < 4; ++nt) acc2[nt] = (f32x4){0.f, 0.f, 0.f, 0.f};
    #pragma unroll
    for (int kc = 0; kc < 4; ++kc) {
        bf16x8 a2 = *(const bf16x8*)&h1s[w * 16 + l15][kc * 32 + quad * 8];
        #pragma unroll
        for (int nt = 0; nt < 4; ++nt) {
            bf16x8 b = *(const bf16x8*)(W2f + (size_t)((kc * 4 + nt) * 64 + l) * 8);
            acc2[nt] = mfma16(a2, b, acc2[nt]);
        }
    }

    // phase 3: per-row dot with W3 via quad shuffle reduction
    float part[4] = {0.f, 0.f, 0.f, 0.f};
    #pragma unroll
    for (int nt = 0; nt < 4; ++nt) {
        int col = nt * 16 + l15;
        float w3v = W3[col];
        float b2v = b2[col];
        #pragma unroll
        for (int reg = 0; reg < 4; ++reg)
            part[reg] += fmaxf(acc2[nt][reg] + b2v, 0.0f) * w3v;
    }
    #pragma unroll
    for (int m = 1; m < 16; m <<= 1) {
        #pragma unroll
        for (int reg = 0; reg < 4; ++reg)
            part[reg] += __shfl_xor(part[reg], m);
    }
    if (l15 < 4) {
        int row = w * 16 + quad * 4 + l15;
        int ee = e0 + row;
        if (ee < E) out[ee] = 1.0f / (1.0f + expf(-(part[l15] + b3[0])));
    }
}

// ---------------------------------------------------------------------------
extern "C" void kernel_launch(void* const* d_in, const int* in_sizes, int n_in,
                              void* d_out, int out_size, void* d_ws, size_t ws_size,
                              hipStream_t stream) {
    const float* x_u     = (const float*)d_in[0];
    const float* x_r     = (const float*)d_in[1];
    const float* eattr   = (const float*)d_in[2];
    const int*   ei_ut   = (const int*)d_in[3];
    const int*   ei_ru   = (const int*)d_in[4];
    const float* proj_uW = (const float*)d_in[5];
    const float* proj_ub = (const float*)d_in[6];
    const float* proj_rW = (const float*)d_in[7];
    const float* proj_rb = (const float*)d_in[8];
    const float* sage_Wl = (const float*)d_in[9];
    const float* sage_bl = (const float*)d_in[10];
    const float* sage_Wr = (const float*)d_in[11];
    const float* bn_g    = (const float*)d_in[12];
    const float* bn_b    = (const float*)d_in[13];
    const float* bn_m    = (const float*)d_in[14];
    const float* bn_v    = (const float*)d_in[15];
    const float* ep_W1   = (const float*)d_in[16];
    const float* ep_b1   = (const float*)d_in[17];
    const float* ep_bng  = (const float*)d_in[18];
    const float* ep_bnb  = (const float*)d_in[19];
    const float* ep_bnm  = (const float*)d_in[20];
    const float* ep_bnv  = (const float*)d_in[21];
    const float* ep_W2   = (const float*)d_in[22];
    const float* ep_b2   = (const float*)d_in[23];
    const float* ep_W3   = (const float*)d_in[24];
    const float* ep_b3   = (const float*)d_in[25];

    int Nu = in_sizes[0] / 32;
    int Nr = in_sizes[1] / 32;
    int E  = in_sizes[3] / 2;

    // ---- workspace carve-up ----
    float* h_u = (float*)d_ws;
    float* h_r = h_u + (size_t)Nu * H;
    unsigned short* us = (unsigned short*)(h_r + (size_t)Nr * H);
    unsigned short* hub    = us;               us += (size_t)Nu * H;
    unsigned short* hrb    = us;               us += (size_t)Nr * H;
    unsigned short* agg_rb = us;               us += (size_t)Nr * H;
    unsigned short* agg_ub = us;               us += (size_t)Nu * H;
    unsigned short* W1f    = us;               us += 36864;
    unsigned short* W2f    = us;               us += 8192;
    unsigned short* puf    = us;               us += 4096;
    unsigned short* prf    = us;               us += 4096;
    unsigned short* sageWf = us;               us += 131072;
    int* ip    = (int*)us;
    int* off_r = ip;  ip += Nr + 1;
    int* off_u = ip;  ip += Nu + 1;
    int* cur_r = ip;  ip += Nr;       // cur_r/cur_u contiguous (one memset)
    int* cur_u = ip;  ip += Nu;
    int* eid_r = ip;  ip += E;
    int* eid_u = ip;  ip += E;
    int* part  = ip;  ip += 512;

    const int* ut_src = ei_ut;
    const int* ut_dst = ei_ut + E;
    const int* ru_src = ei_ru;
    const int* ru_dst = ei_ru + E;

    int EB  = (E + 255) / 256;
    int NBr = (Nr + 255) / 256;
    int NBu = (Nu + 255) / 256;

    // ---- weight fragment prep (idempotent, every call) ----
    wfrag_misc<<<26, 256, 0, stream>>>(ep_W1, ep_W2, proj_uW, proj_rW, W1f, W2f, puf, prf);
    wfrag_sage<<<64, 256, 0, stream>>>(sage_Wl, sage_Wr, sageWf);

    // ---- CSR build (graph identical across layers) ----
    hipMemsetAsync(cur_r, 0, (size_t)(Nr + Nu) * sizeof(int), stream);
    hist_kernel<<<EB, 256, 0, stream>>>(ut_dst, cur_r, E);
    hist_kernel<<<EB, 256, 0, stream>>>(ru_dst, cur_u, E);
    scan1_kernel<<<NBr, 256, 0, stream>>>(cur_r, part, Nr);
    scan2_kernel<<<1, 512, 0, stream>>>(part, NBr);
    scan3_kernel<<<NBr, 256, 0, stream>>>(cur_r, part, off_r, Nr);
    scan1_kernel<<<NBu, 256, 0, stream>>>(cur_u, part, Nu);
    scan2_kernel<<<1, 512, 0, stream>>>(part, NBu);
    scan3_kernel<<<NBu, 256, 0, stream>>>(cur_u, part, off_u, Nu);
    hipMemsetAsync(cur_r, 0, (size_t)(Nr + Nu) * sizeof(int), stream);
    fill_kernel<<<EB, 256, 0, stream>>>(ut_src, ut_dst, off_r, cur_r, eid_r, E);
    fill_kernel<<<EB, 256, 0, stream>>>(ru_src, ru_dst, off_u, cur_u, eid_u, E);

    // ---- input projections (MFMA) ----
    int nbu = (Nu + 63) / 64, nbr = (Nr + 63) / 64;
    proj_kernel<<<nbu + nbr, 256, 0, stream>>>(x_u, x_r, puf, proj_ub, prf, proj_rb,
                                               h_u, h_r, hub, hrb, Nu, Nr, nbu);

    for (int layer = 0; layer < 2; ++layer) {
        gather_kernel<<<(Nr + 3) / 4, 256, 0, stream>>>(hub, eid_r, off_r, agg_rb, Nr);
        gather_kernel<<<(Nu + 3) / 4, 256, 0, stream>>>(hrb, eid_u, off_u, agg_ub, Nu);

        const unsigned short* Wf0 = sageWf + ((size_t)layer * 2 + 0) * 32768;
        const unsigned short* Wf1 = sageWf + ((size_t)layer * 2 + 1) * 32768;
        const float* bl0 = sage_bl + ((size_t)layer * 2 + 0) * H;
        const float* bl1 = sage_bl + ((size_t)layer * 2 + 1) * H;
        const float* g_u = bn_g + ((size_t)layer * 2 + 0) * H;
        const float* b_u = bn_b + ((size_t)layer * 2 + 0) * H;
        const float* m_u = bn_m + ((size_t)layer * 2 + 0) * H;
        const float* v_u = bn_v + ((size_t)layer * 2 + 0) * H;
        const float* g_r = bn_g + ((size_t)layer * 2 + 1) * H;
        const float* b_r = bn_b + ((size_t)layer * 2 + 1) * H;
        const float* m_r = bn_m + ((size_t)layer * 2 + 1) * H;
        const float* v_r = bn_v + ((size_t)layer * 2 + 1) * H;

        sage_kernel<<<(Nr + 63) / 64, 256, 0, stream>>>(agg_rb, h_r, hrb, Nr,
                                                        Wf0, bl0, g_r, b_r, m_r, v_r);
        sage_kernel<<<(Nu + 63) / 64, 256, 0, stream>>>(agg_ub, h_u, hub, Nu,
                                                        Wf1, bl1, g_u, b_u, m_u, v_u);
    }

    ep_kernel<<<(E + 63) / 64, 256, 0, stream>>>(hub, hrb, eattr, ut_src, ut_dst,
                                                 W1f, ep_b1,
                                                 ep_bng, ep_bnb, ep_bnm, ep_bnv,
                                                 W2f, ep_b2, ep_W3, ep_b3,
                                                 (float*)d_out, E);
}

// Round 4
// 567.256 us; speedup vs baseline: 9.3284x; 1.4600x over previous
//
#include <hip/hip_runtime.h>
#include <math.h>

#define H 128
#define BN_EPS 1e-5f

typedef __attribute__((ext_vector_type(8))) short bf16x8;
typedef __attribute__((ext_vector_type(4))) float f32x4;

__device__ __forceinline__ unsigned short f2bf(float f) {
    unsigned int u = __float_as_uint(f);
    u += 0x7fffu + ((u >> 16) & 1u);
    return (unsigned short)(u >> 16);
}
__device__ __forceinline__ float bf2f(unsigned short s) {
    return __uint_as_float(((unsigned int)s) << 16);
}
__device__ __forceinline__ f32x4 mfma16(bf16x8 a, bf16x8 b, f32x4 c) {
    return __builtin_amdgcn_mfma_f32_16x16x32_bf16(a, b, c, 0, 0, 0);
}

// ---------------------------------------------------------------------------
// Weight fragment pre-transpose into MFMA B-operand layout (bf16):
// dst[((kc*ntn+nt)*64+l)*8+j] = src[kc*32+(l>>4)*8+j][nt*16+(l&15)]
// ---------------------------------------------------------------------------
__device__ __forceinline__ void wfrag_one(const float* __restrict__ src,
                                          unsigned short* __restrict__ dst,
                                          int K, int N, int idx) {
    int l = idx & 63;
    int rest = idx >> 6;
    int ntn = N >> 4;
    int nt = rest % ntn;
    int kc = rest / ntn;
    int n = nt * 16 + (l & 15);
    int k0 = kc * 32 + (l >> 4) * 8;
    bf16x8 v;
    #pragma unroll
    for (int j = 0; j < 8; ++j) {
        int k = k0 + j;
        v[j] = (short)((k < K) ? f2bf(src[(size_t)k * N + n]) : 0);
    }
    *(bf16x8*)(dst + (size_t)idx * 8) = v;
}

// one dispatch: ep_W1, ep_W2, proj_u, proj_r, and all 4 sage (Wl|Wr) pairs
__global__ __launch_bounds__(256)
void wfrag_all(const float* __restrict__ W1, const float* __restrict__ W2,
               const float* __restrict__ pu, const float* __restrict__ pr,
               const float* __restrict__ Wl, const float* __restrict__ Wr,
               unsigned short* __restrict__ W1f, unsigned short* __restrict__ W2f,
               unsigned short* __restrict__ puf, unsigned short* __restrict__ prf,
               unsigned short* __restrict__ sageWf) {
    int bx = blockIdx.x;
    if (bx < 26) {
        int idx = bx * 256 + threadIdx.x;
        if (idx < 4608)      wfrag_one(W1, W1f, 272, 128, idx);          // K=272 pad 288
        else if (idx < 5632) wfrag_one(W2, W2f, 128, 64, idx - 4608);
        else if (idx < 6144) wfrag_one(pu, puf, 32, 128, idx - 5632);
        else if (idx < 6656) wfrag_one(pr, prf, 32, 128, idx - 6144);
    } else {
        int idx = (bx - 26) * 256 + threadIdx.x;   // < 16384
        int seg = idx >> 11;                        // 0..7
        int sub = idx & 2047;
        int lt = seg >> 1;                          // layer*2+type
        int half = seg & 1;                         // 0=Wl, 1=Wr
        const float* src = (half ? Wr : Wl) + (size_t)lt * H * H;
        unsigned short* dst = sageWf + (size_t)lt * 32768 + half * 16384;
        wfrag_one(src, dst, 128, 128, sub);
    }
}

// ---------------------------------------------------------------------------
// Input projection via MFMA: hb = bf16(x @ W + b)  (bf16-only output)
// ---------------------------------------------------------------------------
__global__ __launch_bounds__(256)
void proj_kernel(const float* __restrict__ xu, const float* __restrict__ xr,
                 const unsigned short* __restrict__ puf, const float* __restrict__ bu,
                 const unsigned short* __restrict__ prf, const float* __restrict__ br,
                 unsigned short* __restrict__ hub, unsigned short* __restrict__ hrb,
                 int Nu, int Nr, int nbu) {
    int bx = blockIdx.x;
    const float* x; const unsigned short* Wf; const float* bias;
    unsigned short* hb; int N; int row0;
    if (bx < nbu) { x = xu; Wf = puf; bias = bu; hb = hub; N = Nu; row0 = bx * 64; }
    else          { x = xr; Wf = prf; bias = br; hb = hrb; N = Nr; row0 = (bx - nbu) * 64; }

    int tid = threadIdx.x, l = tid & 63, w = tid >> 6, l15 = l & 15, quad = l >> 4;
    int arow = row0 + w * 16 + l15;

    bf16x8 a = {0, 0, 0, 0, 0, 0, 0, 0};
    if (arow < N) {
        const float* xp = x + (size_t)arow * 32 + quad * 8;
        float4 v0 = *(const float4*)xp;
        float4 v1 = *(const float4*)(xp + 4);
        a[0] = (short)f2bf(v0.x); a[1] = (short)f2bf(v0.y);
        a[2] = (short)f2bf(v0.z); a[3] = (short)f2bf(v0.w);
        a[4] = (short)f2bf(v1.x); a[5] = (short)f2bf(v1.y);
        a[6] = (short)f2bf(v1.z); a[7] = (short)f2bf(v1.w);
    }
    f32x4 acc[8];
    #pragma unroll
    for (int nt = 0; nt < 8; ++nt) {
        bf16x8 b = *(const bf16x8*)(Wf + (size_t)(nt * 64 + l) * 8);
        acc[nt] = mfma16(a, b, (f32x4){0.f, 0.f, 0.f, 0.f});
    }
    #pragma unroll
    for (int reg = 0; reg < 4; ++reg) {
        int row = row0 + w * 16 + quad * 4 + reg;
        if (row < N) {
            #pragma unroll
            for (int nt = 0; nt < 8; ++nt) {
                int col = nt * 16 + l15;
                hb[(size_t)row * H + col] = f2bf(acc[nt][reg] + bias[col]);
            }
        }
    }
}

// ---------------------------------------------------------------------------
// CSR build (both edge types in one dispatch each)
// ---------------------------------------------------------------------------
__global__ __launch_bounds__(256)
void hist_kernel(const int* __restrict__ dstR, const int* __restrict__ dstU,
                 int* __restrict__ degR, int* __restrict__ degU, int E, int EB) {
    int bx = blockIdx.x;
    const int* dst = (bx < EB) ? dstR : dstU;
    int* deg = (bx < EB) ? degR : degU;
    int e = ((bx < EB) ? bx : bx - EB) * 256 + threadIdx.x;
    if (e < E) atomicAdd(&deg[dst[e]], 1);
}

__global__ __launch_bounds__(256)
void scan1_kernel(const int* __restrict__ degR, const int* __restrict__ degU,
                  int* __restrict__ partR, int* __restrict__ partU, int Nr, int Nu, int NBr) {
    int bx = blockIdx.x;
    const int* deg = (bx < NBr) ? degR : degU;
    int* part = (bx < NBr) ? partR : partU;
    int lb = (bx < NBr) ? bx : bx - NBr;
    int N = (bx < NBr) ? Nr : Nu;
    __shared__ int s[256];
    int t = threadIdx.x;
    int i = lb * 256 + t;
    s[t] = (i < N) ? deg[i] : 0;
    __syncthreads();
    for (int o = 128; o > 0; o >>= 1) {
        if (t < o) s[t] += s[t + o];
        __syncthreads();
    }
    if (t == 0) part[lb] = s[0];
}

__global__ __launch_bounds__(512)
void scan2_kernel(int* __restrict__ partR, int* __restrict__ partU, int nbR, int nbU) {
    int* part = (blockIdx.x == 0) ? partR : partU;
    int nb = (blockIdx.x == 0) ? nbR : nbU;
    __shared__ int s[512];
    int t = threadIdx.x;
    int v = (t < nb) ? part[t] : 0;
    s[t] = v;
    __syncthreads();
    for (int o = 1; o < 512; o <<= 1) {
        int x = (t >= o) ? s[t - o] : 0;
        __syncthreads();
        s[t] += x;
        __syncthreads();
    }
    if (t < nb) part[t] = s[t] - v;   // exclusive
}

__global__ __launch_bounds__(256)
void scan3_kernel(const int* __restrict__ degR, const int* __restrict__ degU,
                  const int* __restrict__ partR, const int* __restrict__ partU,
                  int* __restrict__ offR, int* __restrict__ offU, int Nr, int Nu, int NBr) {
    int bx = blockIdx.x;
    const int* deg = (bx < NBr) ? degR : degU;
    const int* part = (bx < NBr) ? partR : partU;
    int* off = (bx < NBr) ? offR : offU;
    int lb = (bx < NBr) ? bx : bx - NBr;
    int N = (bx < NBr) ? Nr : Nu;
    __shared__ int s[256];
    int t = threadIdx.x;
    int i = lb * 256 + t;
    int v = (i < N) ? deg[i] : 0;
    s[t] = v;
    __syncthreads();
    for (int o = 1; o < 256; o <<= 1) {
        int x = (t >= o) ? s[t - o] : 0;
        __syncthreads();
        s[t] += x;
        __syncthreads();
    }
    if (i < N) off[i] = part[lb] + s[t] - v;
    if (i == N - 1) off[N] = part[lb] + s[t];
}

// fill consumes deg via atomicSub (no second memset needed)
__global__ __launch_bounds__(256)
void fill_kernel(const int* __restrict__ srcR, const int* __restrict__ dstR,
                 const int* __restrict__ srcU, const int* __restrict__ dstU,
                 const int* __restrict__ offR, const int* __restrict__ offU,
                 int* __restrict__ degR, int* __restrict__ degU,
                 int* __restrict__ eidR, int* __restrict__ eidU, int E, int EB) {
    int bx = blockIdx.x;
    const int* src = (bx < EB) ? srcR : srcU;
    const int* dst = (bx < EB) ? dstR : dstU;
    const int* off = (bx < EB) ? offR : offU;
    int* deg = (bx < EB) ? degR : degU;
    int* eid = (bx < EB) ? eidR : eidU;
    int e = ((bx < EB) ? bx : bx - EB) * 256 + threadIdx.x;
    if (e < E) {
        int d = dst[e];
        int p = off[d] + atomicSub(&deg[d], 1) - 1;
        eid[p] = src[e];
    }
}

// ---------------------------------------------------------------------------
// Fused layer: gather-mean + SAGE + BN + ReLU + residual, both node types.
//   h_new = bf16( relu(bn( mean_{s in nbr} h_old_src[s] @ Wl + bl + h_old_own @ Wr )) + h_old_own )
// Per-lane A-fragment accumulation during the CSR walk (no agg buffer).
// ---------------------------------------------------------------------------
__global__ __launch_bounds__(256)
void layer_kernel(const unsigned short* __restrict__ hu_o, const unsigned short* __restrict__ hr_o,
                  unsigned short* __restrict__ hu_n, unsigned short* __restrict__ hr_n,
                  const int* __restrict__ off_r, const int* __restrict__ eid_r,
                  const int* __restrict__ off_u, const int* __restrict__ eid_u,
                  int Nu, int Nr, int nbr,
                  const unsigned short* __restrict__ WfR, const float* __restrict__ blR,
                  const float* __restrict__ gR, const float* __restrict__ bR,
                  const float* __restrict__ mR, const float* __restrict__ vR,
                  const unsigned short* __restrict__ WfU, const float* __restrict__ blU,
                  const float* __restrict__ gU, const float* __restrict__ bU,
                  const float* __restrict__ mU, const float* __restrict__ vU) {
    int bx = blockIdx.x;
    const unsigned short* gsrc; const unsigned short* own; unsigned short* outp;
    const int* off; const int* eid; const unsigned short* Wf;
    const float *bl, *bg, *bb, *bm, *bv;
    int N, row0;
    if (bx < nbr) {
        gsrc = hu_o; own = hr_o; outp = hr_n; off = off_r; eid = eid_r;
        Wf = WfR; bl = blR; bg = gR; bb = bR; bm = mR; bv = vR;
        N = Nr; row0 = bx * 64;
    } else {
        gsrc = hr_o; own = hu_o; outp = hu_n; off = off_u; eid = eid_u;
        Wf = WfU; bl = blU; bg = gU; bb = bU; bm = mU; bv = vU;
        N = Nu; row0 = (bx - nbr) * 64;
    }

    __shared__ float sc[128], sh[128], bias[128];
    int tid = threadIdx.x;
    if (tid < 128) {
        float s = bg[tid] * rsqrtf(bv[tid] + BN_EPS);
        sc[tid] = s;
        sh[tid] = bb[tid] - bm[tid] * s;
        bias[tid] = bl[tid];
    }
    __syncthreads();

    int l = tid & 63, w = tid >> 6, l15 = l & 15, quad = l >> 4;
    int arow = row0 + w * 16 + l15;
    bool rok = (arow < N);
    size_t rbase = (size_t)(rok ? arow : 0) * H;
    int s0 = rok ? off[arow] : 0;
    int s1 = rok ? off[arow + 1] : 0;

    // gather-mean into per-lane A-fragment slices (4 chunks x 8 elems)
    float ag[4][8];
    #pragma unroll
    for (int kc = 0; kc < 4; ++kc)
        #pragma unroll
        for (int j = 0; j < 8; ++j) ag[kc][j] = 0.0f;

    for (int i = s0; i < s1; ++i) {
        int s = eid[i];
        const unsigned short* rp = gsrc + (size_t)s * H + quad * 8;
        #pragma unroll
        for (int kc = 0; kc < 4; ++kc) {
            bf16x8 v = *(const bf16x8*)(rp + kc * 32);
            #pragma unroll
            for (int j = 0; j < 8; ++j) ag[kc][j] += bf2f((unsigned short)v[j]);
        }
    }
    float inv = (s1 > s0) ? 1.0f / (float)(s1 - s0) : 0.0f;

    f32x4 acc[8];
    #pragma unroll
    for (int nt = 0; nt < 8; ++nt) acc[nt] = (f32x4){0.f, 0.f, 0.f, 0.f};

    // chunks 0..3: aggregated neighbor mean
    #pragma unroll
    for (int kc = 0; kc < 4; ++kc) {
        bf16x8 a;
        #pragma unroll
        for (int j = 0; j < 8; ++j) a[j] = (short)f2bf(ag[kc][j] * inv);
        #pragma unroll
        for (int nt = 0; nt < 8; ++nt) {
            bf16x8 b = *(const bf16x8*)(Wf + (size_t)((kc * 8 + nt) * 64 + l) * 8);
            acc[nt] = mfma16(a, b, acc[nt]);
        }
    }
    // chunks 4..7: own row (root weight)
    #pragma unroll
    for (int kc = 4; kc < 8; ++kc) {
        bf16x8 a = *(const bf16x8*)(own + rbase + (kc - 4) * 32 + quad * 8);
        #pragma unroll
        for (int nt = 0; nt < 8; ++nt) {
            bf16x8 b = *(const bf16x8*)(Wf + (size_t)((kc * 8 + nt) * 64 + l) * 8);
            acc[nt] = mfma16(a, b, acc[nt]);
        }
    }

    // epilogue: bias -> BN -> ReLU -> + residual (bf16)
    #pragma unroll
    for (int reg = 0; reg < 4; ++reg) {
        int crow = row0 + w * 16 + quad * 4 + reg;
        if (crow < N) {
            #pragma unroll
            for (int nt = 0; nt < 8; ++nt) {
                int col = nt * 16 + l15;
                float g = acc[nt][reg] + bias[col];
                g = g * sc[col] + sh[col];
                float hv = bf2f(own[(size_t)crow * H + col]);
                outp[(size_t)crow * H + col] = f2bf(fmaxf(g, 0.0f) + hv);
            }
        }
    }
}

// ---------------------------------------------------------------------------
// Edge predictor via MFMA (unchanged from R3)
// ---------------------------------------------------------------------------
__global__ __launch_bounds__(256)
void ep_kernel(const unsigned short* __restrict__ hub, const unsigned short* __restrict__ hrb,
               const float* __restrict__ ea, const int* __restrict__ esrc,
               const int* __restrict__ edst,
               const unsigned short* __restrict__ W1f, const float* __restrict__ b1,
               const float* __restrict__ bng, const float* __restrict__ bnb,
               const float* __restrict__ bnm, const float* __restrict__ bnv,
               const unsigned short* __restrict__ W2f, const float* __restrict__ b2,
               const float* __restrict__ W3, const float* __restrict__ b3,
               float* __restrict__ out, int E) {
    __shared__ unsigned short h1s[64][136];
    __shared__ int se[64], de[64];
    __shared__ float sc1[128], sh1[128], bi1[128];

    int tid = threadIdx.x;
    int e0 = blockIdx.x * 64;
    if (tid < 64) {
        int e = e0 + tid;
        se[tid] = (e < E) ? esrc[e] : 0;
        de[tid] = (e < E) ? edst[e] : 0;
    }
    if (tid < 128) {
        float s = bng[tid] * rsqrtf(bnv[tid] + BN_EPS);
        sc1[tid] = s;
        sh1[tid] = bnb[tid] - bnm[tid] * s;
        bi1[tid] = b1[tid];
    }
    __syncthreads();

    int l = tid & 63, w = tid >> 6, l15 = l & 15, quad = l >> 4;
    int arow = w * 16 + l15;
    size_t soff = (size_t)se[arow] * H;
    size_t doff = (size_t)de[arow] * H;
    int e = e0 + arow;
    bool ev = (e < E);

    f32x4 acc[8];
    #pragma unroll
    for (int nt = 0; nt < 8; ++nt) acc[nt] = (f32x4){0.f, 0.f, 0.f, 0.f};

    #pragma unroll
    for (int kc = 0; kc < 9; ++kc) {
        bf16x8 a;
        if (kc < 4) {
            a = *(const bf16x8*)(hub + soff + kc * 32 + quad * 8);
        } else if (kc < 8) {
            a = *(const bf16x8*)(hrb + doff + (kc - 4) * 32 + quad * 8);
        } else {
            a = (bf16x8){0, 0, 0, 0, 0, 0, 0, 0};
            if (quad < 2 && ev) {
                const float* p = ea + (size_t)e * 16 + quad * 8;
                float4 v0 = *(const float4*)p;
                float4 v1 = *(const float4*)(p + 4);
                a[0] = (short)f2bf(v0.x); a[1] = (short)f2bf(v0.y);
                a[2] = (short)f2bf(v0.z); a[3] = (short)f2bf(v0.w);
                a[4] = (short)f2bf(v1.x); a[5] = (short)f2bf(v1.y);
                a[6] = (short)f2bf(v1.z); a[7] = (short)f2bf(v1.w);
            }
        }
        #pragma unroll
        for (int nt = 0; nt < 8; ++nt) {
            bf16x8 b = *(const bf16x8*)(W1f + (size_t)((kc * 8 + nt) * 64 + l) * 8);
            acc[nt] = mfma16(a, b, acc[nt]);
        }
    }

    #pragma unroll
    for (int nt = 0; nt < 8; ++nt) {
        #pragma unroll
        for (int reg = 0; reg < 4; ++reg) {
            int row = w * 16 + quad * 4 + reg;
            int col = nt * 16 + l15;
            float z = acc[nt][reg] + bi1[col];
            z = fmaxf(z, 0.0f);
            z = z * sc1[col] + sh1[col];
            h1s[row][col] = f2bf(z);
        }
    }
    __syncthreads();

    f32x4 acc2[4];
    #pragma unroll
    for (int nt = 0; nt < 4; ++nt) acc2[nt] = (f32x4){0.f, 0.f, 0.f, 0.f};
    #pragma unroll
    for (int kc = 0; kc < 4; ++kc) {
        bf16x8 a2 = *(const bf16x8*)&h1s[w * 16 + l15][kc * 32 + quad * 8];
        #pragma unroll
        for (int nt = 0; nt < 4; ++nt) {
            bf16x8 b = *(const bf16x8*)(W2f + (size_t)((kc * 4 + nt) * 64 + l) * 8);
            acc2[nt] = mfma16(a2, b, acc2[nt]);
        }
    }

    float part[4] = {0.f, 0.f, 0.f, 0.f};
    #pragma unroll
    for (int nt = 0; nt < 4; ++nt) {
        int col = nt * 16 + l15;
        float w3v = W3[col];
        float b2v = b2[col];
        #pragma unroll
        for (int reg = 0; reg < 4; ++reg)
            part[reg] += fmaxf(acc2[nt][reg] + b2v, 0.0f) * w3v;
    }
    #pragma unroll
    for (int m = 1; m < 16; m <<= 1) {
        #pragma unroll
        for (int reg = 0; reg < 4; ++reg)
            part[reg] += __shfl_xor(part[reg], m);
    }
    if (l15 < 4) {
        int row = w * 16 + quad * 4 + l15;
        int ee = e0 + row;
        if (ee < E) out[ee] = 1.0f / (1.0f + expf(-(part[l15] + b3[0])));
    }
}

// ---------------------------------------------------------------------------
extern "C" void kernel_launch(void* const* d_in, const int* in_sizes, int n_in,
                              void* d_out, int out_size, void* d_ws, size_t ws_size,
                              hipStream_t stream) {
    const float* x_u     = (const float*)d_in[0];
    const float* x_r     = (const float*)d_in[1];
    const float* eattr   = (const float*)d_in[2];
    const int*   ei_ut   = (const int*)d_in[3];
    const int*   ei_ru   = (const int*)d_in[4];
    const float* proj_uW = (const float*)d_in[5];
    const float* proj_ub = (const float*)d_in[6];
    const float* proj_rW = (const float*)d_in[7];
    const float* proj_rb = (const float*)d_in[8];
    const float* sage_Wl = (const float*)d_in[9];
    const float* sage_bl = (const float*)d_in[10];
    const float* sage_Wr = (const float*)d_in[11];
    const float* bn_g    = (const float*)d_in[12];
    const float* bn_b    = (const float*)d_in[13];
    const float* bn_m    = (const float*)d_in[14];
    const float* bn_v    = (const float*)d_in[15];
    const float* ep_W1   = (const float*)d_in[16];
    const float* ep_b1   = (const float*)d_in[17];
    const float* ep_bng  = (const float*)d_in[18];
    const float* ep_bnb  = (const float*)d_in[19];
    const float* ep_bnm  = (const float*)d_in[20];
    const float* ep_bnv  = (const float*)d_in[21];
    const float* ep_W2   = (const float*)d_in[22];
    const float* ep_b2   = (const float*)d_in[23];
    const float* ep_W3   = (const float*)d_in[24];
    const float* ep_b3   = (const float*)d_in[25];

    int Nu = in_sizes[0] / 32;
    int Nr = in_sizes[1] / 32;
    int E  = in_sizes[3] / 2;

    // ---- workspace (bf16 ping-pong h buffers, frags, CSR) ----
    unsigned short* us = (unsigned short*)d_ws;
    unsigned short* h0_u = us;   us += (size_t)Nu * H;
    unsigned short* h0_r = us;   us += (size_t)Nr * H;
    unsigned short* h1_u = us;   us += (size_t)Nu * H;
    unsigned short* h1_r = us;   us += (size_t)Nr * H;
    unsigned short* W1f  = us;   us += 36864;
    unsigned short* W2f  = us;   us += 8192;
    unsigned short* puf  = us;   us += 4096;
    unsigned short* prf  = us;   us += 4096;
    unsigned short* sageWf = us; us += 131072;
    int* ip    = (int*)us;
    int* off_r = ip;  ip += Nr + 1;
    int* off_u = ip;  ip += Nu + 1;
    int* deg_r = ip;  ip += Nr;      // deg_r/deg_u contiguous (one memset)
    int* deg_u = ip;  ip += Nu;
    int* eid_r = ip;  ip += E;
    int* eid_u = ip;  ip += E;
    int* part_r = ip; ip += 512;
    int* part_u = ip; ip += 512;

    const int* ut_src = ei_ut;
    const int* ut_dst = ei_ut + E;
    const int* ru_src = ei_ru;
    const int* ru_dst = ei_ru + E;

    int EB  = (E + 255) / 256;
    int NBr = (Nr + 255) / 256;
    int NBu = (Nu + 255) / 256;

    // ---- weight fragments (one dispatch) ----
    wfrag_all<<<90, 256, 0, stream>>>(ep_W1, ep_W2, proj_uW, proj_rW,
                                      sage_Wl, sage_Wr,
                                      W1f, W2f, puf, prf, sageWf);

    // ---- CSR build ----
    hipMemsetAsync(deg_r, 0, (size_t)(Nr + Nu) * sizeof(int), stream);
    hist_kernel<<<2 * EB, 256, 0, stream>>>(ut_dst, ru_dst, deg_r, deg_u, E, EB);
    scan1_kernel<<<NBr + NBu, 256, 0, stream>>>(deg_r, deg_u, part_r, part_u, Nr, Nu, NBr);
    scan2_kernel<<<2, 512, 0, stream>>>(part_r, part_u, NBr, NBu);
    scan3_kernel<<<NBr + NBu, 256, 0, stream>>>(deg_r, deg_u, part_r, part_u,
                                                off_r, off_u, Nr, Nu, NBr);
    fill_kernel<<<2 * EB, 256, 0, stream>>>(ut_src, ut_dst, ru_src, ru_dst,
                                            off_r, off_u, deg_r, deg_u,
                                            eid_r, eid_u, E, EB);

    // ---- input projections ----
    int nbu = (Nu + 63) / 64, nbr = (Nr + 63) / 64;
    proj_kernel<<<nbu + nbr, 256, 0, stream>>>(x_u, x_r, puf, proj_ub, prf, proj_rb,
                                               h0_u, h0_r, Nu, Nr, nbu);

    // ---- 2 fused layers (ping-pong h0 -> h1 -> h0) ----
    for (int layer = 0; layer < 2; ++layer) {
        const unsigned short* iu = (layer == 0) ? h0_u : h1_u;
        const unsigned short* ir = (layer == 0) ? h0_r : h1_r;
        unsigned short* ou = (layer == 0) ? h1_u : h0_u;
        unsigned short* orr = (layer == 0) ? h1_r : h0_r;

        const unsigned short* Wf0 = sageWf + ((size_t)layer * 2 + 0) * 32768;
        const unsigned short* Wf1 = sageWf + ((size_t)layer * 2 + 1) * 32768;
        const float* bl0 = sage_bl + ((size_t)layer * 2 + 0) * H;
        const float* bl1 = sage_bl + ((size_t)layer * 2 + 1) * H;
        const float* g0 = bn_g + ((size_t)layer * 2 + 0) * H;   // user BN
        const float* b0 = bn_b + ((size_t)layer * 2 + 0) * H;
        const float* m0 = bn_m + ((size_t)layer * 2 + 0) * H;
        const float* v0 = bn_v + ((size_t)layer * 2 + 0) * H;
        const float* g1 = bn_g + ((size_t)layer * 2 + 1) * H;   // recipient BN
        const float* b1 = bn_b + ((size_t)layer * 2 + 1) * H;
        const float* m1 = bn_m + ((size_t)layer * 2 + 1) * H;
        const float* v1 = bn_v + ((size_t)layer * 2 + 1) * H;

        layer_kernel<<<nbr + nbu, 256, 0, stream>>>(
            iu, ir, ou, orr,
            off_r, eid_r, off_u, eid_u,
            Nu, Nr, nbr,
            Wf0, bl0, g1, b1, m1, v1,    // recipient side (edge type 0, BN type 1)
            Wf1, bl1, g0, b0, m0, v0);   // user side (edge type 1, BN type 0)
    }

    ep_kernel<<<(E + 63) / 64, 256, 0, stream>>>(h0_u, h0_r, eattr, ut_src, ut_dst,
                                                 W1f, ep_b1,
                                                 ep_bng, ep_bnb, ep_bnm, ep_bnv,
                                                 W2f, ep_b2, ep_W3, ep_b3,
                                                 (float*)d_out, E);
}